// Round 1
// baseline (15987.872 us; speedup 1.0000x reference)
//
#include <hip/hip_runtime.h>
#include <hip/hip_bf16.h>

typedef unsigned short u16;
typedef unsigned int u32;

#define NB 32
#define NT 1024
#define ND 192
#define NCH 768
#define NK1 5
#define NK2 3
#define NOUT 512
#define NNODES 7

__device__ __forceinline__ float bf2f(u16 x) { return __uint_as_float(((u32)x) << 16); }
__device__ __forceinline__ u16 f2bf(float f) {
    u32 u = __float_as_uint(f);
    return (u16)((u + 0x7fffu + ((u >> 16) & 1u)) >> 16);
}

// traversal-order weight index for node with path-id g at depth lvl
__constant__ int NODE_IDX[3][4] = {{0, 0, 0, 0}, {1, 4, 0, 0}, {2, 5, 3, 6}};

// ---------------- weight transposes (f32 -> bf16, k-major) ----------------
// W1 (n,br,co,ci,k) -> W1t [n*4+br][k][co][ci]
__global__ void wtrans1(const float* __restrict__ W1, u16* __restrict__ W1t) {
    int idx = blockIdx.x * 256 + threadIdx.x;
    const int total = NNODES * 4 * NK1 * NCH * ND;
    if (idx >= total) return;
    int ci = idx % ND;
    int t = idx / ND;
    int co = t % NCH; t /= NCH;
    int k = t % NK1;  t /= NK1;  // t = n*4+br
    W1t[idx] = f2bf(W1[((size_t)t * NCH + co) * (ND * NK1) + (size_t)ci * NK1 + k]);
}

// W2 (n,br,d,c,k) -> W2t [n*4+br][k][d][c]
__global__ void wtrans2(const float* __restrict__ W2, u16* __restrict__ W2t) {
    int idx = blockIdx.x * 256 + threadIdx.x;
    const int total = NNODES * 4 * NK2 * ND * NCH;
    if (idx >= total) return;
    int c = idx % NCH;
    int t = idx / NCH;
    int d = t % ND;  t /= ND;
    int k = t % NK2; t /= NK2;  // t = n*4+br
    W2t[idx] = f2bf(W2[((size_t)t * ND + d) * (NCH * NK2) + (size_t)c * NK2 + k]);
}

// ---------------- conv1: Cin=192 -> Cout=768, k=5, replication pad 3 -------
// stage 0: input = strided even/odd views of buf (br0=even->phi, br1=odd->psi)
// stage 1: input = dbuf (br0, eta) / cbuf (br1, rho)
// output: h[z][b][t][co] bf16, t in [0, L+2)
__global__ __launch_bounds__(256) void conv1k(
    const float* __restrict__ buf, const float* __restrict__ dbuf,
    const float* __restrict__ cbuf, const u16* __restrict__ W1t,
    const float* __restrict__ b1, u16* __restrict__ h, int lvl, int stage) {
    const int L = 512 >> lvl;
    const int nodes = 1 << lvl;
    const int Lout = L + 2;
    const int tid = threadIdx.x;
    const int co0 = (blockIdx.x % 12) * 64;
    const int t0 = (blockIdx.x / 12) * 64;
    const int b = blockIdx.y;
    const int z = blockIdx.z;
    const int g = z & (nodes - 1);
    const int br = z >> lvl;
    const int n = NODE_IDX[lvl][g];
    const int brw = stage ? (2 + br) : br;

    const float* src;
    int tstr;
    if (stage == 0) {
        src = buf + (size_t)b * (NT * ND) + (size_t)(g + (br << lvl)) * ND;
        tstr = (nodes * 2) * ND;
    } else {
        src = (br ? cbuf : dbuf) + ((size_t)g * NB + b) * (size_t)L * ND;
        tstr = ND;
    }

    __shared__ float xs[68][68];
    __shared__ float ws[64][68];

    float acc[4][4];
#pragma unroll
    for (int j = 0; j < 4; ++j)
#pragma unroll
        for (int i = 0; i < 4; ++i) acc[j][i] = 0.f;

    const int co_l = tid & 15;   // thread co: co0 + co_l + 16*i
    const int t_l = tid >> 4;    // thread t:  t0 + t_l + 16*j
    const u16* wbase = W1t + (size_t)(n * 4 + brw) * (NK1 * NCH * ND);

    for (int ci0 = 0; ci0 < ND; ci0 += 64) {
        __syncthreads();
        for (int idx = tid; idx < 68 * 16; idx += 256) {
            int row = idx >> 4, cc = (idx & 15) << 2;
            int u = t0 + row - 3;
            u = u < 0 ? 0 : (u > L - 1 ? L - 1 : u);
            *(float4*)&xs[row][cc] = *(const float4*)(src + (size_t)u * tstr + ci0 + cc);
        }
        for (int kk = 0; kk < NK1; ++kk) {
            __syncthreads();
            const u16* wk = wbase + ((size_t)kk * NCH + co0) * ND + ci0;
            for (int idx = tid; idx < 64 * 16; idx += 256) {
                int row = idx >> 4, cc = (idx & 15) << 2;
                ushort4 q = *(const ushort4*)(wk + (size_t)row * ND + cc);
                float4 f = {bf2f(q.x), bf2f(q.y), bf2f(q.z), bf2f(q.w)};
                *(float4*)&ws[row][cc] = f;
            }
            __syncthreads();
#pragma unroll
            for (int c4 = 0; c4 < 64; c4 += 4) {
                float4 wr[4], xr[4];
#pragma unroll
                for (int i = 0; i < 4; ++i) wr[i] = *(const float4*)&ws[co_l + 16 * i][c4];
#pragma unroll
                for (int j = 0; j < 4; ++j) xr[j] = *(const float4*)&xs[t_l + 16 * j + kk][c4];
#pragma unroll
                for (int j = 0; j < 4; ++j)
#pragma unroll
                    for (int i = 0; i < 4; ++i)
                        acc[j][i] += xr[j].x * wr[i].x + xr[j].y * wr[i].y +
                                     xr[j].z * wr[i].z + xr[j].w * wr[i].w;
            }
        }
    }

    const float* bb = b1 + (size_t)(n * 4 + brw) * NCH + co0;
    float bias[4];
#pragma unroll
    for (int i = 0; i < 4; ++i) bias[i] = bb[co_l + 16 * i];
    u16* hreg = h + ((size_t)z * NB + b) * (size_t)Lout * NCH;
#pragma unroll
    for (int j = 0; j < 4; ++j) {
        int tt = t0 + t_l + 16 * j;
        if (tt < Lout) {
#pragma unroll
            for (int i = 0; i < 4; ++i) {
                float v = acc[j][i] + bias[i];
                v = v > 0.f ? v : 0.01f * v;
                hreg[(size_t)tt * NCH + co0 + co_l + 16 * i] = f2bf(v);
            }
        }
    }
}

// ---------------- conv2: Cin=768 -> Cout=192, k=3, valid ------------------
// stage 0 epilogue: br0: dbuf = xo*exp(tanh(.)) ; br1: cbuf = xe*exp(tanh(.))
// stage 1 epilogue: br0: buf[even] = cbuf + tanh(.) ; br1: buf[odd] = dbuf - tanh(.)
__global__ __launch_bounds__(256) void conv2k(
    float* __restrict__ buf, float* __restrict__ dbuf, float* __restrict__ cbuf,
    const u16* __restrict__ W2t, const float* __restrict__ b2,
    const u16* __restrict__ h, int lvl, int stage) {
    const int L = 512 >> lvl;
    const int nodes = 1 << lvl;
    const int Lin = L + 2;
    const int tid = threadIdx.x;
    const int co0 = (blockIdx.x % 3) * 64;
    const int t0 = (blockIdx.x / 3) * 64;
    const int b = blockIdx.y;
    const int z = blockIdx.z;
    const int g = z & (nodes - 1);
    const int br = z >> lvl;
    const int n = NODE_IDX[lvl][g];
    const int brw = stage ? (2 + br) : br;

    const u16* hreg = h + ((size_t)z * NB + b) * (size_t)Lin * NCH;
    __shared__ float xs[66][68];
    __shared__ float ws[64][68];

    float acc[4][4];
#pragma unroll
    for (int j = 0; j < 4; ++j)
#pragma unroll
        for (int i = 0; i < 4; ++i) acc[j][i] = 0.f;

    const int co_l = tid & 15;
    const int t_l = tid >> 4;
    const u16* wbase = W2t + (size_t)(n * 4 + brw) * (NK2 * ND * NCH);

    for (int ci0 = 0; ci0 < NCH; ci0 += 64) {
        __syncthreads();
        for (int idx = tid; idx < 66 * 16; idx += 256) {
            int row = idx >> 4, cc = (idx & 15) << 2;
            ushort4 q = *(const ushort4*)(hreg + (size_t)(t0 + row) * NCH + ci0 + cc);
            float4 f = {bf2f(q.x), bf2f(q.y), bf2f(q.z), bf2f(q.w)};
            *(float4*)&xs[row][cc] = f;
        }
        for (int kk = 0; kk < NK2; ++kk) {
            __syncthreads();
            const u16* wk = wbase + ((size_t)kk * ND + co0) * NCH + ci0;
            for (int idx = tid; idx < 64 * 16; idx += 256) {
                int row = idx >> 4, cc = (idx & 15) << 2;
                ushort4 q = *(const ushort4*)(wk + (size_t)row * NCH + cc);
                float4 f = {bf2f(q.x), bf2f(q.y), bf2f(q.z), bf2f(q.w)};
                *(float4*)&ws[row][cc] = f;
            }
            __syncthreads();
#pragma unroll
            for (int c4 = 0; c4 < 64; c4 += 4) {
                float4 wr[4], xr[4];
#pragma unroll
                for (int i = 0; i < 4; ++i) wr[i] = *(const float4*)&ws[co_l + 16 * i][c4];
#pragma unroll
                for (int j = 0; j < 4; ++j) xr[j] = *(const float4*)&xs[t_l + 16 * j + kk][c4];
#pragma unroll
                for (int j = 0; j < 4; ++j)
#pragma unroll
                    for (int i = 0; i < 4; ++i)
                        acc[j][i] += xr[j].x * wr[i].x + xr[j].y * wr[i].y +
                                     xr[j].z * wr[i].z + xr[j].w * wr[i].w;
            }
        }
    }

    const float* bb = b2 + (size_t)(n * 4 + brw) * ND + co0;
    float bias[4];
#pragma unroll
    for (int i = 0; i < 4; ++i) bias[i] = bb[co_l + 16 * i];

    const int tstr = 2 * nodes * ND;
    if (stage == 0) {
        const int mo = g + (br == 0 ? nodes : 0);  // phi multiplies by xo, psi by xe
        const float* mult = buf + (size_t)b * NT * ND + (size_t)mo * ND;
        float* dst = (br == 0 ? dbuf : cbuf) + ((size_t)g * NB + b) * (size_t)L * ND;
#pragma unroll
        for (int j = 0; j < 4; ++j) {
            int t = t0 + t_l + 16 * j;
#pragma unroll
            for (int i = 0; i < 4; ++i) {
                float v = tanhf(acc[j][i] + bias[i]);
                float m = mult[(size_t)t * tstr + co0 + co_l + 16 * i];
                dst[(size_t)t * ND + co0 + co_l + 16 * i] = m * expf(v);
            }
        }
    } else {
        const float* other = (br == 0 ? cbuf : dbuf) + ((size_t)g * NB + b) * (size_t)L * ND;
        const int to = g + (br ? nodes : 0);  // eta->even slots, rho->odd slots
        float* dst = buf + (size_t)b * NT * ND + (size_t)to * ND;
#pragma unroll
        for (int j = 0; j < 4; ++j) {
            int t = t0 + t_l + 16 * j;
#pragma unroll
            for (int i = 0; i < 4; ++i) {
                float v = tanhf(acc[j][i] + bias[i]);
                float o = other[(size_t)t * ND + co0 + co_l + 16 * i];
                dst[(size_t)t * tstr + co0 + co_l + 16 * i] = br == 0 ? (o + v) : (o - v);
            }
        }
    }
}

// ---------------- projection: out[b,o,d] = sum_t (buf+x)[b,t,d]*Wp[o,t] ----
__global__ __launch_bounds__(256) void projk(
    const float* __restrict__ buf, const float* __restrict__ x,
    const float* __restrict__ Wp, float* __restrict__ out) {
    const int tid = threadIdx.x;
    const int o0 = (blockIdx.x & 7) * 64;
    const int d0 = (blockIdx.x >> 3) * 64;
    const int b = blockIdx.y;
    __shared__ float ws[64][68];  // [o][t]
    __shared__ float ss[64][68];  // [d][t]
    float acc[4][4];
#pragma unroll
    for (int j = 0; j < 4; ++j)
#pragma unroll
        for (int i = 0; i < 4; ++i) acc[j][i] = 0.f;
    const int o_l = tid & 15;
    const int d_l = tid >> 4;
    for (int t0 = 0; t0 < NT; t0 += 64) {
        __syncthreads();
        for (int idx = tid; idx < 64 * 16; idx += 256) {
            int row = idx >> 4, cc = (idx & 15) << 2;
            *(float4*)&ws[row][cc] = *(const float4*)(Wp + (size_t)(o0 + row) * NT + t0 + cc);
        }
        for (int idx = tid; idx < 64 * 16; idx += 256) {
            int row = idx >> 4, cc = (idx & 15) << 2;  // row=t, cc=d
            size_t base = (size_t)b * NT * ND + (size_t)(t0 + row) * ND + d0 + cc;
            float4 v1 = *(const float4*)(buf + base);
            float4 v2 = *(const float4*)(x + base);
            ss[cc + 0][row] = v1.x + v2.x;
            ss[cc + 1][row] = v1.y + v2.y;
            ss[cc + 2][row] = v1.z + v2.z;
            ss[cc + 3][row] = v1.w + v2.w;
        }
        __syncthreads();
#pragma unroll
        for (int t4 = 0; t4 < 64; t4 += 4) {
            float4 wr[4], xr[4];
#pragma unroll
            for (int i = 0; i < 4; ++i) wr[i] = *(const float4*)&ws[o_l + 16 * i][t4];
#pragma unroll
            for (int j = 0; j < 4; ++j) xr[j] = *(const float4*)&ss[d_l + 16 * j][t4];
#pragma unroll
            for (int j = 0; j < 4; ++j)
#pragma unroll
                for (int i = 0; i < 4; ++i)
                    acc[j][i] += xr[j].x * wr[i].x + xr[j].y * wr[i].y +
                                 xr[j].z * wr[i].z + xr[j].w * wr[i].w;
        }
    }
#pragma unroll
    for (int j = 0; j < 4; ++j)
#pragma unroll
        for (int i = 0; i < 4; ++i)
            out[((size_t)b * NOUT + o0 + o_l + 16 * i) * ND + d0 + d_l + 16 * j] = acc[j][i];
}

extern "C" void kernel_launch(void* const* d_in, const int* in_sizes, int n_in,
                              void* d_out, int out_size, void* d_ws, size_t ws_size,
                              hipStream_t stream) {
    const float* x = (const float*)d_in[0];
    const float* W1 = (const float*)d_in[1];
    const float* b1 = (const float*)d_in[2];
    const float* W2 = (const float*)d_in[3];
    const float* b2 = (const float*)d_in[4];
    const float* Wp = (const float*)d_in[5];
    float* out = (float*)d_out;

    char* wsb = (char*)d_ws;
    size_t off = 0;
    auto carve = [&](size_t bytes) {
        void* p = wsb + off;
        off += (bytes + 255) & ~(size_t)255;
        return p;
    };
    const size_t w1t_e = (size_t)NNODES * 4 * NK1 * NCH * ND;
    const size_t w2t_e = (size_t)NNODES * 4 * NK2 * ND * NCH;
    const size_t buf_e = (size_t)NB * NT * ND;
    const size_t dc_e = (size_t)NB * 512 * ND;
    const size_t h_e = (size_t)2 * 4 * NB * 130 * NCH;  // max over levels

    u16* W1t = (u16*)carve(sizeof(u16) * w1t_e);
    u16* W2t = (u16*)carve(sizeof(u16) * w2t_e);
    float* buf = (float*)carve(sizeof(float) * buf_e);
    float* dbuf = (float*)carve(sizeof(float) * dc_e);
    float* cbuf = (float*)carve(sizeof(float) * dc_e);
    u16* h = (u16*)carve(sizeof(u16) * h_e);
    if (off > ws_size) return;  // workspace too small: bail (will fail validation cleanly)

    hipMemcpyAsync(buf, x, sizeof(float) * buf_e, hipMemcpyDeviceToDevice, stream);
    wtrans1<<<(int)((w1t_e + 255) / 256), 256, 0, stream>>>(W1, W1t);
    wtrans2<<<(int)((w2t_e + 255) / 256), 256, 0, stream>>>(W2, W2t);

    for (int lvl = 0; lvl < 3; ++lvl) {
        int L = 512 >> lvl, nodes = 1 << lvl;
        int t1 = (L + 2 + 63) / 64, t2 = L / 64;
        dim3 g1(12 * t1, NB, 2 * nodes), g2(3 * t2, NB, 2 * nodes);
        conv1k<<<g1, 256, 0, stream>>>(buf, dbuf, cbuf, W1t, b1, h, lvl, 0);
        conv2k<<<g2, 256, 0, stream>>>(buf, dbuf, cbuf, W2t, b2, h, lvl, 0);
        conv1k<<<g1, 256, 0, stream>>>(buf, dbuf, cbuf, W1t, b1, h, lvl, 1);
        conv2k<<<g2, 256, 0, stream>>>(buf, dbuf, cbuf, W2t, b2, h, lvl, 1);
    }
    projk<<<dim3(24, NB), 256, 0, stream>>>(buf, x, Wp, out);
}

// Round 2
// 986.816 us; speedup vs baseline: 16.2015x; 16.2015x over previous
//
#include <hip/hip_runtime.h>
#include <hip/hip_bf16.h>

typedef unsigned short u16;
typedef unsigned int u32;
typedef __bf16 bf16x8 __attribute__((ext_vector_type(8)));
typedef float f32x4 __attribute__((ext_vector_type(4)));

#define NB 32
#define NT 1024
#define ND 192
#define NCH 768
#define NOUT 512

__device__ __forceinline__ float bf2f(u16 x) { return __uint_as_float(((u32)x) << 16); }
__device__ __forceinline__ u16 f2bf(float f) {
    u32 u = __float_as_uint(f);
    return (u16)((u + 0x7fffu + ((u >> 16) & 1u)) >> 16);
}
__device__ __forceinline__ float tanh_fast(float x) {
    float e = __expf(2.f * x);
    return 1.f - 2.f / (e + 1.f);
}

__constant__ int NODE_IDX[3][4] = {{0, 0, 0, 0}, {1, 4, 0, 0}, {2, 5, 3, 6}};

// ---------- f32 -> bf16 pack (8 elems/thread) ----------
__global__ void cvt8(const float* __restrict__ in, u16* __restrict__ out, int n8) {
    int i = blockIdx.x * 256 + threadIdx.x;
    if (i >= n8) return;
    const float4* p = (const float4*)in + 2 * (size_t)i;
    float4 a = p[0], c = p[1];
    uint4 o;
    o.x = f2bf(a.x) | ((u32)f2bf(a.y) << 16);
    o.y = f2bf(a.z) | ((u32)f2bf(a.w) << 16);
    o.z = f2bf(c.x) | ((u32)f2bf(c.y) << 16);
    o.w = f2bf(c.z) | ((u32)f2bf(c.w) << 16);
    ((uint4*)out)[i] = o;
}

// ---------- W1 (28,768,192,5) f32 -> frag layout [nb][kkb 30][cob 48][lane][8] bf16 ----------
// kk = k*192 + ci ; B-frag: lane l holds B[kk = kkb*32 + 8*(l>>4)+e][co = cob*16 + (l&15)]
__global__ __launch_bounds__(256) void w1fk(const float* __restrict__ W1, u16* __restrict__ W1f) {
    __shared__ u16 ls[32][968];
    const int nb = blockIdx.x / 24;
    const int cot = blockIdx.x % 24;
    const float* src = W1 + ((size_t)nb * NCH + cot * 32) * (ND * 5);
    for (int idx = threadIdx.x; idx < 7680; idx += 256) {
        int e4 = idx * 4;
        int rowc = e4 / 960, col = e4 % 960;
        float4 v = *(const float4*)(src + (size_t)rowc * 960 + col);
        ls[rowc][col + 0] = f2bf(v.x);
        ls[rowc][col + 1] = f2bf(v.y);
        ls[rowc][col + 2] = f2bf(v.z);
        ls[rowc][col + 3] = f2bf(v.w);
    }
    __syncthreads();
    const int lane = threadIdx.x & 63, sub = threadIdx.x >> 6;
    const int g = lane >> 4, r = lane & 15;
    for (int it = 0; it < 15; ++it) {
        int fid = it * 4 + sub;  // 0..59
        int kkb = fid >> 1, cobl = fid & 1;
        u16 tmp[8];
#pragma unroll
        for (int e = 0; e < 8; ++e) {
            int kk = kkb * 32 + 8 * g + e;
            int ci = kk % 192, k = kk / 192;
            tmp[e] = ls[cobl * 16 + r][ci * 5 + k];
        }
        uint4 o;
        o.x = tmp[0] | ((u32)tmp[1] << 16);
        o.y = tmp[2] | ((u32)tmp[3] << 16);
        o.z = tmp[4] | ((u32)tmp[5] << 16);
        o.w = tmp[6] | ((u32)tmp[7] << 16);
        size_t off = (((size_t)nb * 30 + kkb) * 48 + cot * 2 + cobl) * 512 + lane * 8;
        *(uint4*)(W1f + off) = o;
    }
}

// ---------- W2 (28,192,768,3) f32 -> frag layout [nb][kkb 72][cob 12][lane][8] bf16 ----------
// kk = k*768 + c
__global__ __launch_bounds__(256) void w2fk(const float* __restrict__ W2, u16* __restrict__ W2f) {
    __shared__ u16 ls[16][1160];
    const int ch = blockIdx.x & 1;
    const int t = blockIdx.x >> 1;
    const int nb = t / 12, cot = t % 12;
    const float* src = W2 + ((size_t)nb * ND + cot * 16) * (NCH * 3) + ch * 1152;
    for (int idx = threadIdx.x; idx < 4608; idx += 256) {
        int e4 = idx * 4;
        int rowc = e4 / 1152, col = e4 % 1152;
        float4 v = *(const float4*)(src + (size_t)rowc * (NCH * 3) + col);
        ls[rowc][col + 0] = f2bf(v.x);
        ls[rowc][col + 1] = f2bf(v.y);
        ls[rowc][col + 2] = f2bf(v.z);
        ls[rowc][col + 3] = f2bf(v.w);
    }
    __syncthreads();
    const int lane = threadIdx.x & 63, sub = threadIdx.x >> 6;
    const int g = lane >> 4, r = lane & 15;
    for (int it = 0; it < 9; ++it) {
        int fid = it * 4 + sub;  // 0..35
        int k = fid / 12, cib = fid % 12;
        int kkb = k * 24 + ch * 12 + cib;
        u16 tmp[8];
#pragma unroll
        for (int e = 0; e < 8; ++e) {
            int cl = cib * 32 + 8 * g + e;  // c local to this ch half
            tmp[e] = ls[r][cl * 3 + k];
        }
        uint4 o;
        o.x = tmp[0] | ((u32)tmp[1] << 16);
        o.y = tmp[2] | ((u32)tmp[3] << 16);
        o.z = tmp[4] | ((u32)tmp[5] << 16);
        o.w = tmp[6] | ((u32)tmp[7] << 16);
        size_t off = (((size_t)nb * 72 + kkb) * 12 + cot) * 512 + lane * 8;
        *(uint4*)(W2f + off) = o;
    }
}

// ---------- conv1 MFMA: Cin=192, Cout=768, k=5, replication pad 3 ----------
// M rows = flattened (b, t) per z ; output h[z][b][t<Lout][co] bf16
__global__ __launch_bounds__(256) void conv1m(
    const u16* __restrict__ bufb, const u16* __restrict__ dbufb, const u16* __restrict__ cbufb,
    const u16* __restrict__ W1f, const float* __restrict__ b1,
    u16* __restrict__ h, int lvl, int stage) {
    const int L = 512 >> lvl, nodes = 1 << lvl, Lout = L + 2;
    const int tid = threadIdx.x;
    const int cot = blockIdx.x % 6;
    const int mt = blockIdx.x / 6;
    const int z = blockIdx.z;
    const int g_node = z & (nodes - 1);
    const int br = z >> lvl;
    const int nb4 = NODE_IDX[lvl][g_node] * 4 + (stage ? 2 + br : br);

    const int r0 = mt * 128;
    const int b0 = r0 / Lout;
    const int t00 = r0 - b0 * Lout;
    const int s = Lout - t00;  // rows until batch boundary (may exceed 128)
    const int rowsValid0 = NB * Lout - r0;
    const int rowsValid = rowsValid0 < 128 ? rowsValid0 : 128;

    __shared__ u16 xs[136 * 200];  // pitch 200 u16 (400 B)

    const u16* dcb = br ? cbufb : dbufb;
    const int slot = g_node + (br << lvl);
    for (int ch = tid; ch < 136 * 24; ch += 256) {
        int j = ch / 24, c8 = ch % 24;
        int bb, u;
        if (j <= s + 3) { bb = b0; u = t00 - 3 + j; }
        else            { bb = b0 + 1; u = j - s - 7; }
        u = u < 0 ? 0 : (u > L - 1 ? L - 1 : u);
        if (bb > NB - 1) bb = NB - 1;
        const u16* p;
        if (stage == 0)
            p = bufb + ((size_t)bb * NT + slot + (size_t)u * (2 * nodes)) * ND + c8 * 8;
        else
            p = dcb + (((size_t)g_node * NB + bb) * L + u) * (size_t)ND + c8 * 8;
        *(uint4*)(xs + j * 200 + c8 * 8) = *(const uint4*)p;
    }
    __syncthreads();

    const int lane = tid & 63, w = tid >> 6;
    const int wrow = w >> 1, wcol = w & 1;
    const int lr = lane & 15, lg = lane >> 4;

    int arow[4];
#pragma unroll
    for (int m = 0; m < 4; ++m) {
        int i = wrow * 64 + m * 16 + lr;
        arow[m] = (i + (i >= s ? 4 : 0)) * 200 + lg * 8;
    }
    const u16* wf = W1f + (size_t)nb4 * 30 * 48 * 512 + (size_t)(cot * 8 + wcol * 4) * 512 + lane * 8;

    f32x4 acc[4][4];
    f32x4 zz = {0.f, 0.f, 0.f, 0.f};
#pragma unroll
    for (int m = 0; m < 4; ++m)
#pragma unroll
        for (int n = 0; n < 4; ++n) acc[m][n] = zz;

    auto loadA = [&](bf16x8(&dst)[4], int step) {
        const int k = step / 6, cib = step % 6;
#pragma unroll
        for (int m = 0; m < 4; ++m)
            dst[m] = *(const bf16x8*)(xs + arow[m] + k * 200 + cib * 32);
    };
    auto loadB = [&](bf16x8(&dst)[4], int step) {
#pragma unroll
        for (int n = 0; n < 4; ++n)
            dst[n] = *(const bf16x8*)(wf + ((size_t)step * 48 + n) * 512);
    };
    auto domfma = [&](bf16x8(&A)[4], bf16x8(&B)[4]) {
#pragma unroll
        for (int m = 0; m < 4; ++m)
#pragma unroll
            for (int n = 0; n < 4; ++n)
                acc[m][n] = __builtin_amdgcn_mfma_f32_16x16x32_bf16(A[m], B[n], acc[m][n], 0, 0, 0);
    };

    bf16x8 aE[4], bE[4], aO[4], bO[4];
    loadA(aE, 0); loadB(bE, 0);
#pragma unroll
    for (int sp = 0; sp < 15; ++sp) {
        loadA(aO, 2 * sp + 1); loadB(bO, 2 * sp + 1);
        domfma(aE, bE);
        if (sp < 14) { loadA(aE, 2 * sp + 2); loadB(bE, 2 * sp + 2); }
        domfma(aO, bO);
    }

    float bias[4];
    const float* bb1 = b1 + (size_t)nb4 * NCH + cot * 128 + wcol * 64 + lr;
#pragma unroll
    for (int n = 0; n < 4; ++n) bias[n] = bb1[n * 16];
    u16* hz = h + (size_t)z * NB * Lout * NCH;
#pragma unroll
    for (int m = 0; m < 4; ++m) {
#pragma unroll
        for (int rr = 0; rr < 4; ++rr) {
            int i = wrow * 64 + m * 16 + lg * 4 + rr;
            if (i < rowsValid) {
                int cross = (i >= s) ? 1 : 0;
                int bb = b0 + cross;
                int tt = cross ? i - s : t00 + i;
                u16* dst = hz + ((size_t)bb * Lout + tt) * NCH + cot * 128 + wcol * 64 + lr;
#pragma unroll
                for (int n = 0; n < 4; ++n) {
                    float v = acc[m][n][rr] + bias[n];
                    v = v > 0.f ? v : 0.01f * v;
                    dst[n * 16] = f2bf(v);
                }
            }
        }
    }
}

// ---------- conv2 MFMA: Cin=768, Cout=192, k=3, valid + fused epilogues ----------
__global__ __launch_bounds__(256) void conv2m(
    u16* __restrict__ bufb, u16* __restrict__ dbufb, u16* __restrict__ cbufb,
    const u16* __restrict__ W2f, const float* __restrict__ b2,
    const u16* __restrict__ h, int lvl, int stage) {
    const int L = 512 >> lvl, nodes = 1 << lvl, Lout = L + 2;
    const int tid = threadIdx.x;
    const int mt = blockIdx.x;
    const int z = blockIdx.z;
    const int g_node = z & (nodes - 1);
    const int br = z >> lvl;
    const int nb4 = NODE_IDX[lvl][g_node] * 4 + (stage ? 2 + br : br);
    const int r0 = mt * 128;
    const int b = r0 >> (9 - lvl);
    const int t0 = r0 & (L - 1);

    __shared__ u16 xs[130 * 200];
    const u16* hz = h + ((size_t)z * NB + b) * Lout * NCH;

    const int lane = tid & 63, w = tid >> 6;
    const int wrow = w >> 1, wcol = w & 1;
    const int lr = lane & 15, lg = lane >> 4;
    int arow[4];
#pragma unroll
    for (int m = 0; m < 4; ++m) arow[m] = (wrow * 64 + m * 16 + lr) * 200 + lg * 8;
    const u16* wf = W2f + (size_t)nb4 * 72 * 12 * 512 + (size_t)(wcol * 6) * 512 + lane * 8;

    f32x4 acc[4][6];
    f32x4 zz = {0.f, 0.f, 0.f, 0.f};
#pragma unroll
    for (int m = 0; m < 4; ++m)
#pragma unroll
        for (int n = 0; n < 6; ++n) acc[m][n] = zz;

    for (int cc = 0; cc < 4; ++cc) {
        __syncthreads();
        for (int ch = tid; ch < 130 * 24; ch += 256) {
            int j = ch / 24, c8 = ch % 24;
            *(uint4*)(xs + j * 200 + c8 * 8) =
                *(const uint4*)(hz + (size_t)(t0 + j) * NCH + cc * 192 + c8 * 8);
        }
        __syncthreads();
        const u16* wfc = wf + (size_t)cc * 6 * 12 * 512;

        auto loadA = [&](bf16x8(&dst)[4], int step) {
            const int k = step / 6, cib = step % 6;
#pragma unroll
            for (int m = 0; m < 4; ++m)
                dst[m] = *(const bf16x8*)(xs + arow[m] + k * 200 + cib * 32);
        };
        auto loadB = [&](bf16x8(&dst)[6], int step) {
            const int k = step / 6, cib = step % 6;
            const size_t kb = (size_t)(k * 24 + cib) * 12 * 512;
#pragma unroll
            for (int n = 0; n < 6; ++n)
                dst[n] = *(const bf16x8*)(wfc + kb + (size_t)n * 512);
        };
        auto domfma = [&](bf16x8(&A)[4], bf16x8(&B)[6]) {
#pragma unroll
            for (int m = 0; m < 4; ++m)
#pragma unroll
                for (int n = 0; n < 6; ++n)
                    acc[m][n] = __builtin_amdgcn_mfma_f32_16x16x32_bf16(A[m], B[n], acc[m][n], 0, 0, 0);
        };

        bf16x8 aE[4], bE[6], aO[4], bO[6];
        loadA(aE, 0); loadB(bE, 0);
#pragma unroll
        for (int sp = 0; sp < 9; ++sp) {
            loadA(aO, 2 * sp + 1); loadB(bO, 2 * sp + 1);
            domfma(aE, bE);
            if (sp < 8) { loadA(aE, 2 * sp + 2); loadB(bE, 2 * sp + 2); }
            domfma(aO, bO);
        }
    }

    float bias[6];
    const float* bb2 = b2 + (size_t)nb4 * ND + wcol * 96 + lr;
#pragma unroll
    for (int n = 0; n < 6; ++n) bias[n] = bb2[n * 16];

    const int tstr = 2 * nodes;
    if (stage == 0) {
        const int mo = g_node + (br == 0 ? nodes : 0);
        const u16* mult = bufb + ((size_t)b * NT + mo) * ND;
        u16* dst = (br == 0 ? dbufb : cbufb) + ((size_t)g_node * NB + b) * (size_t)L * ND;
#pragma unroll
        for (int m = 0; m < 4; ++m) {
#pragma unroll
            for (int rr = 0; rr < 4; ++rr) {
                int i = wrow * 64 + m * 16 + lg * 4 + rr;
                int t = t0 + i;
#pragma unroll
                for (int n = 0; n < 6; ++n) {
                    int co = wcol * 96 + n * 16 + lr;
                    float v = tanh_fast(acc[m][n][rr] + bias[n]);
                    float mlt = bf2f(mult[(size_t)t * tstr * ND + co]);
                    dst[(size_t)t * ND + co] = f2bf(mlt * __expf(v));
                }
            }
        }
    } else {
        const u16* other = (br == 0 ? cbufb : dbufb) + ((size_t)g_node * NB + b) * (size_t)L * ND;
        const int to = g_node + (br ? nodes : 0);
        u16* dst = bufb + ((size_t)b * NT + to) * ND;
#pragma unroll
        for (int m = 0; m < 4; ++m) {
#pragma unroll
            for (int rr = 0; rr < 4; ++rr) {
                int i = wrow * 64 + m * 16 + lg * 4 + rr;
                int t = t0 + i;
#pragma unroll
                for (int n = 0; n < 6; ++n) {
                    int co = wcol * 96 + n * 16 + lr;
                    float v = tanh_fast(acc[m][n][rr] + bias[n]);
                    float o = bf2f(other[(size_t)t * ND + co]);
                    dst[(size_t)t * tstr * ND + co] = f2bf(br == 0 ? o + v : o - v);
                }
            }
        }
    }
}

// ---------- build in2T[b][d][t] = bf16(buf + x) transposed ----------
__global__ __launch_bounds__(256) void mkin2T(const u16* __restrict__ bufb,
                                              const float* __restrict__ x,
                                              u16* __restrict__ in2T) {
    __shared__ u16 ls[64][72];
    const int b = blockIdx.z, t0 = blockIdx.y * 64, d0 = blockIdx.x * 64;
    const int tid = threadIdx.x;
#pragma unroll
    for (int it = 0; it < 2; ++it) {
        int idx = tid + it * 256;
        int c8 = idx >> 6, row = idx & 63;
        size_t base = ((size_t)b * NT + t0 + row) * ND + d0 + c8 * 8;
        uint4 vb = *(const uint4*)(bufb + base);
        float4 x1 = *(const float4*)(x + base);
        float4 x2 = *(const float4*)(x + base + 4);
        const u16* vs = (const u16*)&vb;
        ls[c8 * 8 + 0][row] = f2bf(bf2f(vs[0]) + x1.x);
        ls[c8 * 8 + 1][row] = f2bf(bf2f(vs[1]) + x1.y);
        ls[c8 * 8 + 2][row] = f2bf(bf2f(vs[2]) + x1.z);
        ls[c8 * 8 + 3][row] = f2bf(bf2f(vs[3]) + x1.w);
        ls[c8 * 8 + 4][row] = f2bf(bf2f(vs[4]) + x2.x);
        ls[c8 * 8 + 5][row] = f2bf(bf2f(vs[5]) + x2.y);
        ls[c8 * 8 + 6][row] = f2bf(bf2f(vs[6]) + x2.z);
        ls[c8 * 8 + 7][row] = f2bf(bf2f(vs[7]) + x2.w);
    }
    __syncthreads();
#pragma unroll
    for (int it = 0; it < 2; ++it) {
        int idx = tid + it * 256;
        int dl = idx >> 3, t8 = idx & 7;
        uint4 v = *(uint4*)&ls[dl][t8 * 8];
        *(uint4*)(in2T + ((size_t)b * ND + d0 + dl) * NT + t0 + t8 * 8) = v;
    }
}

// ---------- projection MFMA: out[b][o][d] = sum_t Wp[o][t]*(buf+x)[t][d] ----------
__global__ __launch_bounds__(256) void projm(const u16* __restrict__ in2T,
                                             const u16* __restrict__ Wpb,
                                             float* __restrict__ out) {
    const int b = blockIdx.y, ot = blockIdx.x;
    const int tid = threadIdx.x, lane = tid & 63, wcol = tid >> 6;
    const int lr = lane & 15, lg = lane >> 4;
    const u16* ap = Wpb + ((size_t)(ot * 64 + lr)) * NT + lg * 8;
    const u16* bp = in2T + ((size_t)b * ND + wcol * 48 + lr) * NT + lg * 8;

    f32x4 acc[4][3];
    f32x4 zz = {0.f, 0.f, 0.f, 0.f};
#pragma unroll
    for (int m = 0; m < 4; ++m)
#pragma unroll
        for (int n = 0; n < 3; ++n) acc[m][n] = zz;

    auto loadA = [&](bf16x8(&dst)[4], int kkb) {
#pragma unroll
        for (int m = 0; m < 4; ++m)
            dst[m] = *(const bf16x8*)(ap + (size_t)m * 16 * NT + kkb * 32);
    };
    auto loadB = [&](bf16x8(&dst)[3], int kkb) {
#pragma unroll
        for (int n = 0; n < 3; ++n)
            dst[n] = *(const bf16x8*)(bp + (size_t)n * 16 * NT + kkb * 32);
    };
    auto domfma = [&](bf16x8(&A)[4], bf16x8(&B)[3]) {
#pragma unroll
        for (int m = 0; m < 4; ++m)
#pragma unroll
            for (int n = 0; n < 3; ++n)
                acc[m][n] = __builtin_amdgcn_mfma_f32_16x16x32_bf16(A[m], B[n], acc[m][n], 0, 0, 0);
    };

    bf16x8 aE[4], bE[3], aO[4], bO[3];
    loadA(aE, 0); loadB(bE, 0);
#pragma unroll
    for (int sp = 0; sp < 16; ++sp) {
        loadA(aO, 2 * sp + 1); loadB(bO, 2 * sp + 1);
        domfma(aE, bE);
        if (sp < 15) { loadA(aE, 2 * sp + 2); loadB(bE, 2 * sp + 2); }
        domfma(aO, bO);
    }

#pragma unroll
    for (int m = 0; m < 4; ++m)
#pragma unroll
        for (int rr = 0; rr < 4; ++rr) {
            int o = ot * 64 + m * 16 + lg * 4 + rr;
#pragma unroll
            for (int n = 0; n < 3; ++n) {
                int d = wcol * 48 + n * 16 + lr;
                out[((size_t)b * NOUT + o) * ND + d] = acc[m][n][rr];
            }
        }
}

extern "C" void kernel_launch(void* const* d_in, const int* in_sizes, int n_in,
                              void* d_out, int out_size, void* d_ws, size_t ws_size,
                              hipStream_t stream) {
    const float* x = (const float*)d_in[0];
    const float* W1 = (const float*)d_in[1];
    const float* b1 = (const float*)d_in[2];
    const float* W2 = (const float*)d_in[3];
    const float* b2 = (const float*)d_in[4];
    const float* Wp = (const float*)d_in[5];
    float* out = (float*)d_out;

    char* wsb = (char*)d_ws;
    size_t off = 0;
    auto carve = [&](size_t bytes) {
        void* p = wsb + off;
        off += (bytes + 255) & ~(size_t)255;
        return p;
    };
    const size_t w1f_e = (size_t)28 * 30 * 48 * 512;
    const size_t w2f_e = (size_t)28 * 72 * 12 * 512;
    const size_t wpb_e = (size_t)NOUT * NT;
    const size_t buf_e = (size_t)NB * NT * ND;
    const size_t dc_e = (size_t)NB * 512 * ND;
    const size_t h_e = (size_t)1040 * NB * NCH;  // max over levels of (2*nodes)*Lout rows
    const size_t i2_e = (size_t)NB * ND * NT;

    u16* W1f = (u16*)carve(sizeof(u16) * w1f_e);
    u16* W2f = (u16*)carve(sizeof(u16) * w2f_e);
    u16* Wpb = (u16*)carve(sizeof(u16) * wpb_e);
    u16* bufb = (u16*)carve(sizeof(u16) * buf_e);
    u16* dbufb = (u16*)carve(sizeof(u16) * dc_e);
    u16* cbufb = (u16*)carve(sizeof(u16) * dc_e);
    u16* h = (u16*)carve(sizeof(u16) * h_e);
    u16* in2T = (u16*)carve(sizeof(u16) * i2_e);
    if (off > ws_size) return;

    cvt8<<<(int)(buf_e / 8 / 256), 256, 0, stream>>>(x, bufb, (int)(buf_e / 8));
    cvt8<<<(int)(wpb_e / 8 / 256), 256, 0, stream>>>(Wp, Wpb, (int)(wpb_e / 8));
    w1fk<<<28 * 24, 256, 0, stream>>>(W1, W1f);
    w2fk<<<28 * 12 * 2, 256, 0, stream>>>(W2, W2f);

    for (int lvl = 0; lvl < 3; ++lvl) {
        int L = 512 >> lvl, nodes = 1 << lvl, Lout = L + 2;
        int mT1 = (NB * Lout + 127) / 128;
        int mT2 = NB * L / 128;
        dim3 g1(6 * mT1, 1, 2 * nodes), g2(mT2, 1, 2 * nodes);
        conv1m<<<g1, 256, 0, stream>>>(bufb, dbufb, cbufb, W1f, b1, h, lvl, 0);
        conv2m<<<g2, 256, 0, stream>>>(bufb, dbufb, cbufb, W2f, b2, h, lvl, 0);
        conv1m<<<g1, 256, 0, stream>>>(bufb, dbufb, cbufb, W1f, b1, h, lvl, 1);
        conv2m<<<g2, 256, 0, stream>>>(bufb, dbufb, cbufb, W2f, b2, h, lvl, 1);
    }
    mkin2T<<<dim3(3, 16, NB), 256, 0, stream>>>(bufb, x, in2T);
    projm<<<dim3(8, NB), 256, 0, stream>>>(in2T, Wpb, out);
}

// Round 3
// 799.378 us; speedup vs baseline: 20.0004x; 1.2345x over previous
//
#include <hip/hip_runtime.h>
#include <hip/hip_bf16.h>

typedef unsigned short u16;
typedef unsigned int u32;
typedef __bf16 bf16x8 __attribute__((ext_vector_type(8)));
typedef float f32x4 __attribute__((ext_vector_type(4)));

#define NB 32
#define NT 1024
#define ND 192
#define NCH 768
#define NOUT 512

__device__ __forceinline__ float bf2f(u16 x) { return __uint_as_float(((u32)x) << 16); }
__device__ __forceinline__ u16 f2bf(float f) {
    u32 u = __float_as_uint(f);
    return (u16)((u + 0x7fffu + ((u >> 16) & 1u)) >> 16);
}
__device__ __forceinline__ float tanh_fast(float x) {
    float e = __expf(2.f * x);
    return 1.f - 2.f / (e + 1.f);
}

__constant__ int NODE_IDX[3][4] = {{0, 0, 0, 0}, {1, 4, 0, 0}, {2, 5, 3, 6}};

// ---------- f32 -> bf16 pack (8 elems/thread) ----------
__global__ void cvt8(const float* __restrict__ in, u16* __restrict__ out, int n8) {
    int i = blockIdx.x * 256 + threadIdx.x;
    if (i >= n8) return;
    const float4* p = (const float4*)in + 2 * (size_t)i;
    float4 a = p[0], c = p[1];
    uint4 o;
    o.x = f2bf(a.x) | ((u32)f2bf(a.y) << 16);
    o.y = f2bf(a.z) | ((u32)f2bf(a.w) << 16);
    o.z = f2bf(c.x) | ((u32)f2bf(c.y) << 16);
    o.w = f2bf(c.z) | ((u32)f2bf(c.w) << 16);
    ((uint4*)out)[i] = o;
}

// ---------- W1 (28,768,192,5) f32 -> frag layout [nb][kkb 30][cob 48][lane][8] bf16 ----------
__global__ __launch_bounds__(256) void w1fk(const float* __restrict__ W1, u16* __restrict__ W1f) {
    __shared__ u16 ls[32][968];
    const int nb = blockIdx.x / 24;
    const int cot = blockIdx.x % 24;
    const float* src = W1 + ((size_t)nb * NCH + cot * 32) * (ND * 5);
    for (int idx = threadIdx.x; idx < 7680; idx += 256) {
        int e4 = idx * 4;
        int rowc = e4 / 960, col = e4 % 960;
        float4 v = *(const float4*)(src + (size_t)rowc * 960 + col);
        ls[rowc][col + 0] = f2bf(v.x);
        ls[rowc][col + 1] = f2bf(v.y);
        ls[rowc][col + 2] = f2bf(v.z);
        ls[rowc][col + 3] = f2bf(v.w);
    }
    __syncthreads();
    const int lane = threadIdx.x & 63, sub = threadIdx.x >> 6;
    const int g = lane >> 4, r = lane & 15;
    for (int it = 0; it < 15; ++it) {
        int fid = it * 4 + sub;
        int kkb = fid >> 1, cobl = fid & 1;
        u16 tmp[8];
#pragma unroll
        for (int e = 0; e < 8; ++e) {
            int kk = kkb * 32 + 8 * g + e;
            int ci = kk % 192, k = kk / 192;
            tmp[e] = ls[cobl * 16 + r][ci * 5 + k];
        }
        uint4 o;
        o.x = tmp[0] | ((u32)tmp[1] << 16);
        o.y = tmp[2] | ((u32)tmp[3] << 16);
        o.z = tmp[4] | ((u32)tmp[5] << 16);
        o.w = tmp[6] | ((u32)tmp[7] << 16);
        size_t off = (((size_t)nb * 30 + kkb) * 48 + cot * 2 + cobl) * 512 + lane * 8;
        *(uint4*)(W1f + off) = o;
    }
}

// ---------- W2 (28,192,768,3) f32 -> frag layout [nb][kkb 72][cob 12][lane][8] bf16 ----------
__global__ __launch_bounds__(256) void w2fk(const float* __restrict__ W2, u16* __restrict__ W2f) {
    __shared__ u16 ls[16][1160];
    const int ch = blockIdx.x & 1;
    const int t = blockIdx.x >> 1;
    const int nb = t / 12, cot = t % 12;
    const float* src = W2 + ((size_t)nb * ND + cot * 16) * (NCH * 3) + ch * 1152;
    for (int idx = threadIdx.x; idx < 4608; idx += 256) {
        int e4 = idx * 4;
        int rowc = e4 / 1152, col = e4 % 1152;
        float4 v = *(const float4*)(src + (size_t)rowc * (NCH * 3) + col);
        ls[rowc][col + 0] = f2bf(v.x);
        ls[rowc][col + 1] = f2bf(v.y);
        ls[rowc][col + 2] = f2bf(v.z);
        ls[rowc][col + 3] = f2bf(v.w);
    }
    __syncthreads();
    const int lane = threadIdx.x & 63, sub = threadIdx.x >> 6;
    const int g = lane >> 4, r = lane & 15;
    for (int it = 0; it < 9; ++it) {
        int fid = it * 4 + sub;
        int k = fid / 12, cib = fid % 12;
        int kkb = k * 24 + ch * 12 + cib;
        u16 tmp[8];
#pragma unroll
        for (int e = 0; e < 8; ++e) {
            int cl = cib * 32 + 8 * g + e;
            tmp[e] = ls[r][cl * 3 + k];
        }
        uint4 o;
        o.x = tmp[0] | ((u32)tmp[1] << 16);
        o.y = tmp[2] | ((u32)tmp[3] << 16);
        o.z = tmp[4] | ((u32)tmp[5] << 16);
        o.w = tmp[6] | ((u32)tmp[7] << 16);
        size_t off = (((size_t)nb * 72 + kkb) * 12 + cot) * 512 + lane * 8;
        *(uint4*)(W2f + off) = o;
    }
}

// ---------- conv1 MFMA: Cin=192, Cout=768, k=5, replication pad 3 ----------
__global__ __launch_bounds__(256) void conv1m(
    const u16* __restrict__ bufb, const u16* __restrict__ dbufb, const u16* __restrict__ cbufb,
    const u16* __restrict__ W1f, const float* __restrict__ b1,
    u16* __restrict__ h, int lvl, int stage) {
    const int L = 512 >> lvl, nodes = 1 << lvl, Lout = L + 2;
    const int tid = threadIdx.x;
    const int cot = blockIdx.x % 6;
    const int mt = blockIdx.x / 6;
    const int z = blockIdx.z;
    const int g_node = z & (nodes - 1);
    const int br = z >> lvl;
    const int nb4 = NODE_IDX[lvl][g_node] * 4 + (stage ? 2 + br : br);

    const int r0 = mt * 128;
    const int b0 = r0 / Lout;
    const int t00 = r0 - b0 * Lout;
    const int s = Lout - t00;
    const int rowsValid0 = NB * Lout - r0;
    const int rowsValid = rowsValid0 < 128 ? rowsValid0 : 128;

    __shared__ u16 xs[136 * 192];  // pitch 192, XOR-swizzled 16B chunks

    const u16* dcb = br ? cbufb : dbufb;
    const int slot = g_node + (br << lvl);
    for (int ch = tid; ch < 136 * 24; ch += 256) {
        int j = ch / 24, c8 = ch % 24;
        int bb, u;
        if (j <= s + 3) { bb = b0; u = t00 - 3 + j; }
        else            { bb = b0 + 1; u = j - s - 7; }
        u = u < 0 ? 0 : (u > L - 1 ? L - 1 : u);
        if (bb > NB - 1) bb = NB - 1;
        const u16* p;
        if (stage == 0)
            p = bufb + ((size_t)bb * NT + slot + (size_t)u * (2 * nodes)) * ND + c8 * 8;
        else
            p = dcb + (((size_t)g_node * NB + bb) * L + u) * (size_t)ND + c8 * 8;
        *(uint4*)(xs + j * 192 + ((c8 * 8) ^ ((j & 7) << 3))) = *(const uint4*)p;
    }
    __syncthreads();

    const int lane = tid & 63, w = tid >> 6;
    const int wrow = w >> 1, wcol = w & 1;
    const int lr = lane & 15, lg = lane >> 4;

    int rowb[4];
#pragma unroll
    for (int m = 0; m < 4; ++m) {
        int i = wrow * 64 + m * 16 + lr;
        rowb[m] = i + (i >= s ? 4 : 0);
    }
    const u16* wf = W1f + (size_t)nb4 * 30 * 48 * 512 + (size_t)(cot * 8 + wcol * 4) * 512 + lane * 8;

    f32x4 acc[4][4];
    f32x4 zz = {0.f, 0.f, 0.f, 0.f};
#pragma unroll
    for (int m = 0; m < 4; ++m)
#pragma unroll
        for (int n = 0; n < 4; ++n) acc[m][n] = zz;

    auto loadA = [&](bf16x8(&dst)[4], int step) {
        const int k = step / 6, cib = step % 6;
#pragma unroll
        for (int m = 0; m < 4; ++m) {
            int row = rowb[m] + k;
            int idx = row * 192 + ((cib * 32 + lg * 8) ^ ((row & 7) << 3));
            dst[m] = *(const bf16x8*)(xs + idx);
        }
    };
    auto loadB = [&](bf16x8(&dst)[4], int step) {
#pragma unroll
        for (int n = 0; n < 4; ++n)
            dst[n] = *(const bf16x8*)(wf + ((size_t)step * 48 + n) * 512);
    };
    auto domfma = [&](bf16x8(&A)[4], bf16x8(&B)[4]) {
#pragma unroll
        for (int m = 0; m < 4; ++m)
#pragma unroll
            for (int n = 0; n < 4; ++n)
                acc[m][n] = __builtin_amdgcn_mfma_f32_16x16x32_bf16(A[m], B[n], acc[m][n], 0, 0, 0);
    };

    bf16x8 aE[4], bE[4], aO[4], bO[4];
    loadA(aE, 0); loadB(bE, 0);
#pragma unroll
    for (int sp = 0; sp < 15; ++sp) {
        loadA(aO, 2 * sp + 1); loadB(bO, 2 * sp + 1);
        domfma(aE, bE);
        if (sp < 14) { loadA(aE, 2 * sp + 2); loadB(bE, 2 * sp + 2); }
        domfma(aO, bO);
    }

    float bias[4];
    const float* bb1 = b1 + (size_t)nb4 * NCH + cot * 128 + wcol * 64 + lr;
#pragma unroll
    for (int n = 0; n < 4; ++n) bias[n] = bb1[n * 16];
    u16* hz = h + (size_t)z * NB * Lout * NCH;
#pragma unroll
    for (int m = 0; m < 4; ++m) {
#pragma unroll
        for (int rr = 0; rr < 4; ++rr) {
            int i = wrow * 64 + m * 16 + lg * 4 + rr;
            if (i < rowsValid) {
                int cross = (i >= s) ? 1 : 0;
                int bb = b0 + cross;
                int tt = cross ? i - s : t00 + i;
                u16* dst = hz + ((size_t)bb * Lout + tt) * NCH + cot * 128 + wcol * 64 + lr;
#pragma unroll
                for (int n = 0; n < 4; ++n) {
                    float v = acc[m][n][rr] + bias[n];
                    v = v > 0.f ? v : 0.01f * v;
                    dst[n * 16] = f2bf(v);
                }
            }
        }
    }
}

// ---------- conv2 MFMA: Cin=768, Cout=192, k=3, valid + fused epilogues ----------
// M-tile 64 rows, N-split 2x96 -> 1024 blocks at every level (4/CU)
__global__ __launch_bounds__(256) void conv2m(
    u16* __restrict__ bufb, u16* __restrict__ dbufb, u16* __restrict__ cbufb,
    const u16* __restrict__ W2f, const float* __restrict__ b2,
    const u16* __restrict__ h, int lvl, int stage) {
    const int L = 512 >> lvl, nodes = 1 << lvl, Lout = L + 2;
    const int tid = threadIdx.x;
    const int mt = blockIdx.x;
    const int nh = blockIdx.y;  // 0/1: cols nh*96..nh*96+95
    const int z = blockIdx.z;
    const int g_node = z & (nodes - 1);
    const int br = z >> lvl;
    const int nb4 = NODE_IDX[lvl][g_node] * 4 + (stage ? 2 + br : br);
    const int r0 = mt * 64;
    const int b = r0 >> (9 - lvl);
    const int t0 = r0 & (L - 1);

    __shared__ u16 xs[66 * 192];
    const u16* hz = h + ((size_t)z * NB + b) * Lout * NCH;

    const int lane = tid & 63, w = tid >> 6;
    const int wrow = w >> 1, wcol = w & 1;
    const int lr = lane & 15, lg = lane >> 4;
    int rowb[2];
#pragma unroll
    for (int m = 0; m < 2; ++m) rowb[m] = wrow * 32 + m * 16 + lr;
    const u16* wf = W2f + (size_t)nb4 * 72 * 12 * 512 + (size_t)(nh * 6 + wcol * 3) * 512 + lane * 8;

    f32x4 acc[2][3];
    f32x4 zz = {0.f, 0.f, 0.f, 0.f};
#pragma unroll
    for (int m = 0; m < 2; ++m)
#pragma unroll
        for (int n = 0; n < 3; ++n) acc[m][n] = zz;

    for (int cc = 0; cc < 4; ++cc) {
        __syncthreads();
        for (int ch = tid; ch < 66 * 24; ch += 256) {
            int j = ch / 24, c8 = ch % 24;
            *(uint4*)(xs + j * 192 + ((c8 * 8) ^ ((j & 7) << 3))) =
                *(const uint4*)(hz + (size_t)(t0 + j) * NCH + cc * 192 + c8 * 8);
        }
        __syncthreads();

        auto loadA = [&](bf16x8(&dst)[2], int step) {
            const int k = step / 6, cib = step % 6;
#pragma unroll
            for (int m = 0; m < 2; ++m) {
                int row = rowb[m] + k;
                int idx = row * 192 + ((cib * 32 + lg * 8) ^ ((row & 7) << 3));
                dst[m] = *(const bf16x8*)(xs + idx);
            }
        };
        auto loadB = [&](bf16x8(&dst)[3], int step) {
            const int k = step / 6, cib = step % 6;
            const size_t kb = (size_t)(cc * 6 + k * 24 + cib) * 12 * 512;
#pragma unroll
            for (int n = 0; n < 3; ++n)
                dst[n] = *(const bf16x8*)(wf + kb + (size_t)n * 512);
        };
        auto domfma = [&](bf16x8(&A)[2], bf16x8(&B)[3]) {
#pragma unroll
            for (int m = 0; m < 2; ++m)
#pragma unroll
                for (int n = 0; n < 3; ++n)
                    acc[m][n] = __builtin_amdgcn_mfma_f32_16x16x32_bf16(A[m], B[n], acc[m][n], 0, 0, 0);
        };

        bf16x8 aE[2], bE[3], aO[2], bO[3];
        loadA(aE, 0); loadB(bE, 0);
#pragma unroll
        for (int sp = 0; sp < 9; ++sp) {
            loadA(aO, 2 * sp + 1); loadB(bO, 2 * sp + 1);
            domfma(aE, bE);
            if (sp < 8) { loadA(aE, 2 * sp + 2); loadB(bE, 2 * sp + 2); }
            domfma(aO, bO);
        }
    }

    float bias[3];
    const float* bb2 = b2 + (size_t)nb4 * ND + nh * 96 + wcol * 48 + lr;
#pragma unroll
    for (int n = 0; n < 3; ++n) bias[n] = bb2[n * 16];

    const int tstr = 2 * nodes;
    if (stage == 0) {
        const int mo = g_node + (br == 0 ? nodes : 0);
        const u16* mult = bufb + ((size_t)b * NT + mo) * ND;
        u16* dst = (br == 0 ? dbufb : cbufb) + ((size_t)g_node * NB + b) * (size_t)L * ND;
#pragma unroll
        for (int m = 0; m < 2; ++m) {
#pragma unroll
            for (int rr = 0; rr < 4; ++rr) {
                int i = wrow * 32 + m * 16 + lg * 4 + rr;
                int t = t0 + i;
#pragma unroll
                for (int n = 0; n < 3; ++n) {
                    int co = nh * 96 + wcol * 48 + n * 16 + lr;
                    float v = tanh_fast(acc[m][n][rr] + bias[n]);
                    float mlt = bf2f(mult[(size_t)t * tstr * ND + co]);
                    dst[(size_t)t * ND + co] = f2bf(mlt * __expf(v));
                }
            }
        }
    } else {
        const u16* other = (br == 0 ? cbufb : dbufb) + ((size_t)g_node * NB + b) * (size_t)L * ND;
        const int to = g_node + (br ? nodes : 0);
        u16* dst = bufb + ((size_t)b * NT + to) * ND;
#pragma unroll
        for (int m = 0; m < 2; ++m) {
#pragma unroll
            for (int rr = 0; rr < 4; ++rr) {
                int i = wrow * 32 + m * 16 + lg * 4 + rr;
                int t = t0 + i;
#pragma unroll
                for (int n = 0; n < 3; ++n) {
                    int co = nh * 96 + wcol * 48 + n * 16 + lr;
                    float v = tanh_fast(acc[m][n][rr] + bias[n]);
                    float o = bf2f(other[(size_t)t * ND + co]);
                    dst[(size_t)t * tstr * ND + co] = f2bf(br == 0 ? o + v : o - v);
                }
            }
        }
    }
}

// ---------- build in2T[b][d][t] = bf16(buf + x) transposed ----------
__global__ __launch_bounds__(256) void mkin2T(const u16* __restrict__ bufb,
                                              const float* __restrict__ x,
                                              u16* __restrict__ in2T) {
    __shared__ u16 ls[64][72];
    const int b = blockIdx.z, t0 = blockIdx.y * 64, d0 = blockIdx.x * 64;
    const int tid = threadIdx.x;
#pragma unroll
    for (int it = 0; it < 2; ++it) {
        int idx = tid + it * 256;
        int c8 = idx >> 6, row = idx & 63;
        size_t base = ((size_t)b * NT + t0 + row) * ND + d0 + c8 * 8;
        uint4 vb = *(const uint4*)(bufb + base);
        float4 x1 = *(const float4*)(x + base);
        float4 x2 = *(const float4*)(x + base + 4);
        const u16* vs = (const u16*)&vb;
        ls[c8 * 8 + 0][row] = f2bf(bf2f(vs[0]) + x1.x);
        ls[c8 * 8 + 1][row] = f2bf(bf2f(vs[1]) + x1.y);
        ls[c8 * 8 + 2][row] = f2bf(bf2f(vs[2]) + x1.z);
        ls[c8 * 8 + 3][row] = f2bf(bf2f(vs[3]) + x1.w);
        ls[c8 * 8 + 4][row] = f2bf(bf2f(vs[4]) + x2.x);
        ls[c8 * 8 + 5][row] = f2bf(bf2f(vs[5]) + x2.y);
        ls[c8 * 8 + 6][row] = f2bf(bf2f(vs[6]) + x2.z);
        ls[c8 * 8 + 7][row] = f2bf(bf2f(vs[7]) + x2.w);
    }
    __syncthreads();
#pragma unroll
    for (int it = 0; it < 2; ++it) {
        int idx = tid + it * 256;
        int dl = idx >> 3, t8 = idx & 7;
        uint4 v = *(uint4*)&ls[dl][t8 * 8];
        *(uint4*)(in2T + ((size_t)b * ND + d0 + dl) * NT + t0 + t8 * 8) = v;
    }
}

// ---------- projection MFMA: out[b][o][d] = sum_t Wp[o][t]*(buf+x)[t][d] ----------
__global__ __launch_bounds__(256) void projm(const u16* __restrict__ in2T,
                                             const u16* __restrict__ Wpb,
                                             float* __restrict__ out) {
    const int b = blockIdx.y, ot = blockIdx.x;  // 32 output rows per block
    const int tid = threadIdx.x, lane = tid & 63, w = tid >> 6;
    const int lr = lane & 15, lg = lane >> 4;
    const u16* ap = Wpb + ((size_t)(ot * 32 + lr)) * NT + lg * 8;
    const u16* bp = in2T + ((size_t)b * ND + w * 48 + lr) * NT + lg * 8;

    f32x4 acc[2][3];
    f32x4 zz = {0.f, 0.f, 0.f, 0.f};
#pragma unroll
    for (int m = 0; m < 2; ++m)
#pragma unroll
        for (int n = 0; n < 3; ++n) acc[m][n] = zz;

    auto loadA = [&](bf16x8(&dst)[2], int kkb) {
#pragma unroll
        for (int m = 0; m < 2; ++m)
            dst[m] = *(const bf16x8*)(ap + (size_t)m * 16 * NT + kkb * 32);
    };
    auto loadB = [&](bf16x8(&dst)[3], int kkb) {
#pragma unroll
        for (int n = 0; n < 3; ++n)
            dst[n] = *(const bf16x8*)(bp + (size_t)n * 16 * NT + kkb * 32);
    };
    auto domfma = [&](bf16x8(&A)[2], bf16x8(&B)[3]) {
#pragma unroll
        for (int m = 0; m < 2; ++m)
#pragma unroll
            for (int n = 0; n < 3; ++n)
                acc[m][n] = __builtin_amdgcn_mfma_f32_16x16x32_bf16(A[m], B[n], acc[m][n], 0, 0, 0);
    };

    bf16x8 aE[2], bE[3], aO[2], bO[3];
    loadA(aE, 0); loadB(bE, 0);
#pragma unroll
    for (int sp = 0; sp < 16; ++sp) {
        loadA(aO, 2 * sp + 1); loadB(bO, 2 * sp + 1);
        domfma(aE, bE);
        if (sp < 15) { loadA(aE, 2 * sp + 2); loadB(bE, 2 * sp + 2); }
        domfma(aO, bO);
    }

#pragma unroll
    for (int m = 0; m < 2; ++m)
#pragma unroll
        for (int rr = 0; rr < 4; ++rr) {
            int o = ot * 32 + m * 16 + lg * 4 + rr;
#pragma unroll
            for (int n = 0; n < 3; ++n) {
                int d = w * 48 + n * 16 + lr;
                out[((size_t)b * NOUT + o) * ND + d] = acc[m][n][rr];
            }
        }
}

extern "C" void kernel_launch(void* const* d_in, const int* in_sizes, int n_in,
                              void* d_out, int out_size, void* d_ws, size_t ws_size,
                              hipStream_t stream) {
    const float* x = (const float*)d_in[0];
    const float* W1 = (const float*)d_in[1];
    const float* b1 = (const float*)d_in[2];
    const float* W2 = (const float*)d_in[3];
    const float* b2 = (const float*)d_in[4];
    const float* Wp = (const float*)d_in[5];
    float* out = (float*)d_out;

    char* wsb = (char*)d_ws;
    size_t off = 0;
    auto carve = [&](size_t bytes) {
        void* p = wsb + off;
        off += (bytes + 255) & ~(size_t)255;
        return p;
    };
    const size_t w1f_e = (size_t)28 * 30 * 48 * 512;
    const size_t w2f_e = (size_t)28 * 72 * 12 * 512;
    const size_t wpb_e = (size_t)NOUT * NT;
    const size_t buf_e = (size_t)NB * NT * ND;
    const size_t dc_e = (size_t)NB * 512 * ND;
    const size_t h_e = (size_t)1040 * NB * NCH;
    const size_t i2_e = (size_t)NB * ND * NT;

    u16* W1f = (u16*)carve(sizeof(u16) * w1f_e);
    u16* W2f = (u16*)carve(sizeof(u16) * w2f_e);
    u16* Wpb = (u16*)carve(sizeof(u16) * wpb_e);
    u16* bufb = (u16*)carve(sizeof(u16) * buf_e);
    u16* dbufb = (u16*)carve(sizeof(u16) * dc_e);
    u16* cbufb = (u16*)carve(sizeof(u16) * dc_e);
    u16* h = (u16*)carve(sizeof(u16) * h_e);
    u16* in2T = (u16*)carve(sizeof(u16) * i2_e);
    if (off > ws_size) return;

    cvt8<<<(int)(buf_e / 8 / 256), 256, 0, stream>>>(x, bufb, (int)(buf_e / 8));
    cvt8<<<(int)(wpb_e / 8 / 256), 256, 0, stream>>>(Wp, Wpb, (int)(wpb_e / 8));
    w1fk<<<28 * 24, 256, 0, stream>>>(W1, W1f);
    w2fk<<<28 * 12 * 2, 256, 0, stream>>>(W2, W2f);

    for (int lvl = 0; lvl < 3; ++lvl) {
        int L = 512 >> lvl, nodes = 1 << lvl, Lout = L + 2;
        int mT1 = (NB * Lout + 127) / 128;
        dim3 g1(6 * mT1, 1, 2 * nodes);
        dim3 g2(NB * L / 64, 2, 2 * nodes);
        conv1m<<<g1, 256, 0, stream>>>(bufb, dbufb, cbufb, W1f, b1, h, lvl, 0);
        conv2m<<<g2, 256, 0, stream>>>(bufb, dbufb, cbufb, W2f, b2, h, lvl, 0);
        conv1m<<<g1, 256, 0, stream>>>(bufb, dbufb, cbufb, W1f, b1, h, lvl, 1);
        conv2m<<<g2, 256, 0, stream>>>(bufb, dbufb, cbufb, W2f, b2, h, lvl, 1);
    }
    mkin2T<<<dim3(3, 16, NB), 256, 0, stream>>>(bufb, x, in2T);
    projm<<<dim3(16, NB), 256, 0, stream>>>(in2T, Wpb, out);
}

// Round 4
// 776.962 us; speedup vs baseline: 20.5774x; 1.0289x over previous
//
#include <hip/hip_runtime.h>
#include <hip/hip_bf16.h>

typedef unsigned short u16;
typedef unsigned int u32;
typedef __bf16 bf16x8 __attribute__((ext_vector_type(8)));
typedef float f32x4 __attribute__((ext_vector_type(4)));

#define NB 32
#define NT 1024
#define ND 192
#define NCH 768
#define NOUT 512

__device__ __forceinline__ float bf2f(u16 x) { return __uint_as_float(((u32)x) << 16); }
__device__ __forceinline__ u16 f2bf(float f) {
    u32 u = __float_as_uint(f);
    return (u16)((u + 0x7fffu + ((u >> 16) & 1u)) >> 16);
}
__device__ __forceinline__ float tanh_fast(float x) {
    float e = __expf(2.f * x);
    return 1.f - 2.f / (e + 1.f);
}

__constant__ int NODE_IDX[3][4] = {{0, 0, 0, 0}, {1, 4, 0, 0}, {2, 5, 3, 6}};

// ---------- f32 -> bf16 pack (8 elems/thread) ----------
__global__ void cvt8(const float* __restrict__ in, u16* __restrict__ out, int n8) {
    int i = blockIdx.x * 256 + threadIdx.x;
    if (i >= n8) return;
    const float4* p = (const float4*)in + 2 * (size_t)i;
    float4 a = p[0], c = p[1];
    uint4 o;
    o.x = f2bf(a.x) | ((u32)f2bf(a.y) << 16);
    o.y = f2bf(a.z) | ((u32)f2bf(a.w) << 16);
    o.z = f2bf(c.x) | ((u32)f2bf(c.y) << 16);
    o.w = f2bf(c.z) | ((u32)f2bf(c.w) << 16);
    ((uint4*)out)[i] = o;
}

// ---------- W1 (28,768,192,5) f32 -> frag layout [nb][kkb 30][cob 48][lane][8] bf16 ----------
__global__ __launch_bounds__(256) void w1fk(const float* __restrict__ W1, u16* __restrict__ W1f) {
    __shared__ u16 ls[32][968];
    const int nb = blockIdx.x / 24;
    const int cot = blockIdx.x % 24;
    const float* src = W1 + ((size_t)nb * NCH + cot * 32) * (ND * 5);
    for (int idx = threadIdx.x; idx < 7680; idx += 256) {
        int e4 = idx * 4;
        int rowc = e4 / 960, col = e4 % 960;
        float4 v = *(const float4*)(src + (size_t)rowc * 960 + col);
        ls[rowc][col + 0] = f2bf(v.x);
        ls[rowc][col + 1] = f2bf(v.y);
        ls[rowc][col + 2] = f2bf(v.z);
        ls[rowc][col + 3] = f2bf(v.w);
    }
    __syncthreads();
    const int lane = threadIdx.x & 63, sub = threadIdx.x >> 6;
    const int g = lane >> 4, r = lane & 15;
    for (int it = 0; it < 15; ++it) {
        int fid = it * 4 + sub;
        int kkb = fid >> 1, cobl = fid & 1;
        u16 tmp[8];
#pragma unroll
        for (int e = 0; e < 8; ++e) {
            int kk = kkb * 32 + 8 * g + e;
            int ci = kk % 192, k = kk / 192;
            tmp[e] = ls[cobl * 16 + r][ci * 5 + k];
        }
        uint4 o;
        o.x = tmp[0] | ((u32)tmp[1] << 16);
        o.y = tmp[2] | ((u32)tmp[3] << 16);
        o.z = tmp[4] | ((u32)tmp[5] << 16);
        o.w = tmp[6] | ((u32)tmp[7] << 16);
        size_t off = (((size_t)nb * 30 + kkb) * 48 + cot * 2 + cobl) * 512 + lane * 8;
        *(uint4*)(W1f + off) = o;
    }
}

// ---------- W2 (28,192,768,3) f32 -> frag layout [nb][kkb 72][cob 12][lane][8] bf16 ----------
__global__ __launch_bounds__(256) void w2fk(const float* __restrict__ W2, u16* __restrict__ W2f) {
    __shared__ u16 ls[16][1160];
    const int ch = blockIdx.x & 1;
    const int t = blockIdx.x >> 1;
    const int nb = t / 12, cot = t % 12;
    const float* src = W2 + ((size_t)nb * ND + cot * 16) * (NCH * 3) + ch * 1152;
    for (int idx = threadIdx.x; idx < 4608; idx += 256) {
        int e4 = idx * 4;
        int rowc = e4 / 1152, col = e4 % 1152;
        float4 v = *(const float4*)(src + (size_t)rowc * (NCH * 3) + col);
        ls[rowc][col + 0] = f2bf(v.x);
        ls[rowc][col + 1] = f2bf(v.y);
        ls[rowc][col + 2] = f2bf(v.z);
        ls[rowc][col + 3] = f2bf(v.w);
    }
    __syncthreads();
    const int lane = threadIdx.x & 63, sub = threadIdx.x >> 6;
    const int g = lane >> 4, r = lane & 15;
    for (int it = 0; it < 9; ++it) {
        int fid = it * 4 + sub;
        int k = fid / 12, cib = fid % 12;
        int kkb = k * 24 + ch * 12 + cib;
        u16 tmp[8];
#pragma unroll
        for (int e = 0; e < 8; ++e) {
            int cl = cib * 32 + 8 * g + e;
            tmp[e] = ls[r][cl * 3 + k];
        }
        uint4 o;
        o.x = tmp[0] | ((u32)tmp[1] << 16);
        o.y = tmp[2] | ((u32)tmp[3] << 16);
        o.z = tmp[4] | ((u32)tmp[5] << 16);
        o.w = tmp[6] | ((u32)tmp[7] << 16);
        size_t off = (((size_t)nb * 72 + kkb) * 12 + cot) * 512 + lane * 8;
        *(uint4*)(W2f + off) = o;
    }
}

// ---------- conv1 MFMA: Cin=192, Cout=768, k=5, replication pad 3 ----------
// M-tile 64 rows -> LDS 27.6 KB, 5 blocks/CU (occupancy lever, mirrors conv2m)
__global__ __launch_bounds__(256) void conv1m(
    const u16* __restrict__ bufb, const u16* __restrict__ dbufb, const u16* __restrict__ cbufb,
    const u16* __restrict__ W1f, const float* __restrict__ b1,
    u16* __restrict__ h, int lvl, int stage) {
    const int L = 512 >> lvl, nodes = 1 << lvl, Lout = L + 2;
    const int tid = threadIdx.x;
    const int cot = blockIdx.x % 6;
    const int mt = blockIdx.x / 6;
    const int z = blockIdx.z;
    const int g_node = z & (nodes - 1);
    const int br = z >> lvl;
    const int nb4 = NODE_IDX[lvl][g_node] * 4 + (stage ? 2 + br : br);

    const int r0 = mt * 64;
    const int b0 = r0 / Lout;
    const int t00 = r0 - b0 * Lout;
    const int s = Lout - t00;  // rows until batch boundary (may exceed 64)
    const int rowsValid0 = NB * Lout - r0;
    const int rowsValid = rowsValid0 < 64 ? rowsValid0 : 64;

    __shared__ u16 xs[72 * 192];  // pitch 192, XOR-swizzled 16B chunks

    const u16* dcb = br ? cbufb : dbufb;
    const int slot = g_node + (br << lvl);
    for (int ch = tid; ch < 72 * 24; ch += 256) {
        int j = ch / 24, c8 = ch % 24;
        int bb, u;
        if (j <= s + 3) { bb = b0; u = t00 - 3 + j; }
        else            { bb = b0 + 1; u = j - s - 7; }
        u = u < 0 ? 0 : (u > L - 1 ? L - 1 : u);
        if (bb > NB - 1) bb = NB - 1;
        const u16* p;
        if (stage == 0)
            p = bufb + ((size_t)bb * NT + slot + (size_t)u * (2 * nodes)) * ND + c8 * 8;
        else
            p = dcb + (((size_t)g_node * NB + bb) * L + u) * (size_t)ND + c8 * 8;
        *(uint4*)(xs + j * 192 + ((c8 * 8) ^ ((j & 7) << 3))) = *(const uint4*)p;
    }
    __syncthreads();

    const int lane = tid & 63, w = tid >> 6;
    const int wrow = w >> 1, wcol = w & 1;
    const int lr = lane & 15, lg = lane >> 4;

    int rowb[2];
#pragma unroll
    for (int m = 0; m < 2; ++m) {
        int i = wrow * 32 + m * 16 + lr;
        rowb[m] = i + (i >= s ? 4 : 0);
    }
    const u16* wf = W1f + (size_t)nb4 * 30 * 48 * 512 + (size_t)(cot * 8 + wcol * 4) * 512 + lane * 8;

    f32x4 acc[2][4];
    f32x4 zz = {0.f, 0.f, 0.f, 0.f};
#pragma unroll
    for (int m = 0; m < 2; ++m)
#pragma unroll
        for (int n = 0; n < 4; ++n) acc[m][n] = zz;

    auto loadA = [&](bf16x8(&dst)[2], int step) {
        const int k = step / 6, cib = step % 6;
#pragma unroll
        for (int m = 0; m < 2; ++m) {
            int row = rowb[m] + k;
            int idx = row * 192 + ((cib * 32 + lg * 8) ^ ((row & 7) << 3));
            dst[m] = *(const bf16x8*)(xs + idx);
        }
    };
    auto loadB = [&](bf16x8(&dst)[4], int step) {
#pragma unroll
        for (int n = 0; n < 4; ++n)
            dst[n] = *(const bf16x8*)(wf + ((size_t)step * 48 + n) * 512);
    };
    auto domfma = [&](bf16x8(&A)[2], bf16x8(&B)[4]) {
#pragma unroll
        for (int m = 0; m < 2; ++m)
#pragma unroll
            for (int n = 0; n < 4; ++n)
                acc[m][n] = __builtin_amdgcn_mfma_f32_16x16x32_bf16(A[m], B[n], acc[m][n], 0, 0, 0);
    };

    bf16x8 aE[2], bE[4], aO[2], bO[4];
    loadA(aE, 0); loadB(bE, 0);
#pragma unroll
    for (int sp = 0; sp < 15; ++sp) {
        loadA(aO, 2 * sp + 1); loadB(bO, 2 * sp + 1);
        domfma(aE, bE);
        if (sp < 14) { loadA(aE, 2 * sp + 2); loadB(bE, 2 * sp + 2); }
        domfma(aO, bO);
    }

    float bias[4];
    const float* bb1 = b1 + (size_t)nb4 * NCH + cot * 128 + wcol * 64 + lr;
#pragma unroll
    for (int n = 0; n < 4; ++n) bias[n] = bb1[n * 16];
    u16* hz = h + (size_t)z * NB * Lout * NCH;
#pragma unroll
    for (int m = 0; m < 2; ++m) {
#pragma unroll
        for (int rr = 0; rr < 4; ++rr) {
            int i = wrow * 32 + m * 16 + lg * 4 + rr;
            if (i < rowsValid) {
                int cross = (i >= s) ? 1 : 0;
                int bb = b0 + cross;
                int tt = cross ? i - s : t00 + i;
                u16* dst = hz + ((size_t)bb * Lout + tt) * NCH + cot * 128 + wcol * 64 + lr;
#pragma unroll
                for (int n = 0; n < 4; ++n) {
                    float v = acc[m][n][rr] + bias[n];
                    v = v > 0.f ? v : 0.01f * v;
                    dst[n * 16] = f2bf(v);
                }
            }
        }
    }
}

// ---------- conv2 MFMA: Cin=768, Cout=192, k=3, valid + fused epilogues ----------
__global__ __launch_bounds__(256) void conv2m(
    u16* __restrict__ bufb, u16* __restrict__ dbufb, u16* __restrict__ cbufb,
    const u16* __restrict__ W2f, const float* __restrict__ b2,
    const u16* __restrict__ h, int lvl, int stage) {
    const int L = 512 >> lvl, nodes = 1 << lvl, Lout = L + 2;
    const int tid = threadIdx.x;
    const int mt = blockIdx.x;
    const int nh = blockIdx.y;
    const int z = blockIdx.z;
    const int g_node = z & (nodes - 1);
    const int br = z >> lvl;
    const int nb4 = NODE_IDX[lvl][g_node] * 4 + (stage ? 2 + br : br);
    const int r0 = mt * 64;
    const int b = r0 >> (9 - lvl);
    const int t0 = r0 & (L - 1);

    __shared__ u16 xs[66 * 192];
    const u16* hz = h + ((size_t)z * NB + b) * Lout * NCH;

    const int lane = tid & 63, w = tid >> 6;
    const int wrow = w >> 1, wcol = w & 1;
    const int lr = lane & 15, lg = lane >> 4;
    int rowb[2];
#pragma unroll
    for (int m = 0; m < 2; ++m) rowb[m] = wrow * 32 + m * 16 + lr;
    const u16* wf = W2f + (size_t)nb4 * 72 * 12 * 512 + (size_t)(nh * 6 + wcol * 3) * 512 + lane * 8;

    f32x4 acc[2][3];
    f32x4 zz = {0.f, 0.f, 0.f, 0.f};
#pragma unroll
    for (int m = 0; m < 2; ++m)
#pragma unroll
        for (int n = 0; n < 3; ++n) acc[m][n] = zz;

    for (int cc = 0; cc < 4; ++cc) {
        __syncthreads();
        for (int ch = tid; ch < 66 * 24; ch += 256) {
            int j = ch / 24, c8 = ch % 24;
            *(uint4*)(xs + j * 192 + ((c8 * 8) ^ ((j & 7) << 3))) =
                *(const uint4*)(hz + (size_t)(t0 + j) * NCH + cc * 192 + c8 * 8);
        }
        __syncthreads();

        auto loadA = [&](bf16x8(&dst)[2], int step) {
            const int k = step / 6, cib = step % 6;
#pragma unroll
            for (int m = 0; m < 2; ++m) {
                int row = rowb[m] + k;
                int idx = row * 192 + ((cib * 32 + lg * 8) ^ ((row & 7) << 3));
                dst[m] = *(const bf16x8*)(xs + idx);
            }
        };
        auto loadB = [&](bf16x8(&dst)[3], int step) {
            const int k = step / 6, cib = step % 6;
            const size_t kb = (size_t)(cc * 6 + k * 24 + cib) * 12 * 512;
#pragma unroll
            for (int n = 0; n < 3; ++n)
                dst[n] = *(const bf16x8*)(wf + kb + (size_t)n * 512);
        };
        auto domfma = [&](bf16x8(&A)[2], bf16x8(&B)[3]) {
#pragma unroll
            for (int m = 0; m < 2; ++m)
#pragma unroll
                for (int n = 0; n < 3; ++n)
                    acc[m][n] = __builtin_amdgcn_mfma_f32_16x16x32_bf16(A[m], B[n], acc[m][n], 0, 0, 0);
        };

        bf16x8 aE[2], bE[3], aO[2], bO[3];
        loadA(aE, 0); loadB(bE, 0);
#pragma unroll
        for (int sp = 0; sp < 9; ++sp) {
            loadA(aO, 2 * sp + 1); loadB(bO, 2 * sp + 1);
            domfma(aE, bE);
            if (sp < 8) { loadA(aE, 2 * sp + 2); loadB(bE, 2 * sp + 2); }
            domfma(aO, bO);
        }
    }

    float bias[3];
    const float* bb2 = b2 + (size_t)nb4 * ND + nh * 96 + wcol * 48 + lr;
#pragma unroll
    for (int n = 0; n < 3; ++n) bias[n] = bb2[n * 16];

    const int tstr = 2 * nodes;
    if (stage == 0) {
        const int mo = g_node + (br == 0 ? nodes : 0);
        const u16* mult = bufb + ((size_t)b * NT + mo) * ND;
        u16* dst = (br == 0 ? dbufb : cbufb) + ((size_t)g_node * NB + b) * (size_t)L * ND;
#pragma unroll
        for (int m = 0; m < 2; ++m) {
#pragma unroll
            for (int rr = 0; rr < 4; ++rr) {
                int i = wrow * 32 + m * 16 + lg * 4 + rr;
                int t = t0 + i;
#pragma unroll
                for (int n = 0; n < 3; ++n) {
                    int co = nh * 96 + wcol * 48 + n * 16 + lr;
                    float v = tanh_fast(acc[m][n][rr] + bias[n]);
                    float mlt = bf2f(mult[(size_t)t * tstr * ND + co]);
                    dst[(size_t)t * ND + co] = f2bf(mlt * __expf(v));
                }
            }
        }
    } else {
        const u16* other = (br == 0 ? cbufb : dbufb) + ((size_t)g_node * NB + b) * (size_t)L * ND;
        const int to = g_node + (br ? nodes : 0);
        u16* dst = bufb + ((size_t)b * NT + to) * ND;
#pragma unroll
        for (int m = 0; m < 2; ++m) {
#pragma unroll
            for (int rr = 0; rr < 4; ++rr) {
                int i = wrow * 32 + m * 16 + lg * 4 + rr;
                int t = t0 + i;
#pragma unroll
                for (int n = 0; n < 3; ++n) {
                    int co = nh * 96 + wcol * 48 + n * 16 + lr;
                    float v = tanh_fast(acc[m][n][rr] + bias[n]);
                    float o = bf2f(other[(size_t)t * ND + co]);
                    dst[(size_t)t * tstr * ND + co] = f2bf(br == 0 ? o + v : o - v);
                }
            }
        }
    }
}

// ---------- build in2T[b][d][t] = bf16(buf + x) transposed ----------
__global__ __launch_bounds__(256) void mkin2T(const u16* __restrict__ bufb,
                                              const float* __restrict__ x,
                                              u16* __restrict__ in2T) {
    __shared__ u16 ls[64][72];
    const int b = blockIdx.z, t0 = blockIdx.y * 64, d0 = blockIdx.x * 64;
    const int tid = threadIdx.x;
#pragma unroll
    for (int it = 0; it < 2; ++it) {
        int idx = tid + it * 256;
        int c8 = idx >> 6, row = idx & 63;
        size_t base = ((size_t)b * NT + t0 + row) * ND + d0 + c8 * 8;
        uint4 vb = *(const uint4*)(bufb + base);
        float4 x1 = *(const float4*)(x + base);
        float4 x2 = *(const float4*)(x + base + 4);
        const u16* vs = (const u16*)&vb;
        ls[c8 * 8 + 0][row] = f2bf(bf2f(vs[0]) + x1.x);
        ls[c8 * 8 + 1][row] = f2bf(bf2f(vs[1]) + x1.y);
        ls[c8 * 8 + 2][row] = f2bf(bf2f(vs[2]) + x1.z);
        ls[c8 * 8 + 3][row] = f2bf(bf2f(vs[3]) + x1.w);
        ls[c8 * 8 + 4][row] = f2bf(bf2f(vs[4]) + x2.x);
        ls[c8 * 8 + 5][row] = f2bf(bf2f(vs[5]) + x2.y);
        ls[c8 * 8 + 6][row] = f2bf(bf2f(vs[6]) + x2.z);
        ls[c8 * 8 + 7][row] = f2bf(bf2f(vs[7]) + x2.w);
    }
    __syncthreads();
#pragma unroll
    for (int it = 0; it < 2; ++it) {
        int idx = tid + it * 256;
        int dl = idx >> 3, t8 = idx & 7;
        uint4 v = *(uint4*)&ls[dl][t8 * 8];
        *(uint4*)(in2T + ((size_t)b * ND + d0 + dl) * NT + t0 + t8 * 8) = v;
    }
}

// ---------- projection MFMA: out[b][o][d] = sum_t Wp[o][t]*(buf+x)[t][d] ----------
__global__ __launch_bounds__(256) void projm(const u16* __restrict__ in2T,
                                             const u16* __restrict__ Wpb,
                                             float* __restrict__ out) {
    const int b = blockIdx.y, ot = blockIdx.x;
    const int tid = threadIdx.x, lane = tid & 63, w = tid >> 6;
    const int lr = lane & 15, lg = lane >> 4;
    const u16* ap = Wpb + ((size_t)(ot * 32 + lr)) * NT + lg * 8;
    const u16* bp = in2T + ((size_t)b * ND + w * 48 + lr) * NT + lg * 8;

    f32x4 acc[2][3];
    f32x4 zz = {0.f, 0.f, 0.f, 0.f};
#pragma unroll
    for (int m = 0; m < 2; ++m)
#pragma unroll
        for (int n = 0; n < 3; ++n) acc[m][n] = zz;

    auto loadA = [&](bf16x8(&dst)[2], int kkb) {
#pragma unroll
        for (int m = 0; m < 2; ++m)
            dst[m] = *(const bf16x8*)(ap + (size_t)m * 16 * NT + kkb * 32);
    };
    auto loadB = [&](bf16x8(&dst)[3], int kkb) {
#pragma unroll
        for (int n = 0; n < 3; ++n)
            dst[n] = *(const bf16x8*)(bp + (size_t)n * 16 * NT + kkb * 32);
    };
    auto domfma = [&](bf16x8(&A)[2], bf16x8(&B)[3]) {
#pragma unroll
        for (int m = 0; m < 2; ++m)
#pragma unroll
            for (int n = 0; n < 3; ++n)
                acc[m][n] = __builtin_amdgcn_mfma_f32_16x16x32_bf16(A[m], B[n], acc[m][n], 0, 0, 0);
    };

    bf16x8 aE[2], bE[3], aO[2], bO[3];
    loadA(aE, 0); loadB(bE, 0);
#pragma unroll
    for (int sp = 0; sp < 16; ++sp) {
        loadA(aO, 2 * sp + 1); loadB(bO, 2 * sp + 1);
        domfma(aE, bE);
        if (sp < 15) { loadA(aE, 2 * sp + 2); loadB(bE, 2 * sp + 2); }
        domfma(aO, bO);
    }

#pragma unroll
    for (int m = 0; m < 2; ++m)
#pragma unroll
        for (int rr = 0; rr < 4; ++rr) {
            int o = ot * 32 + m * 16 + lg * 4 + rr;
#pragma unroll
            for (int n = 0; n < 3; ++n) {
                int d = w * 48 + n * 16 + lr;
                out[((size_t)b * NOUT + o) * ND + d] = acc[m][n][rr];
            }
        }
}

extern "C" void kernel_launch(void* const* d_in, const int* in_sizes, int n_in,
                              void* d_out, int out_size, void* d_ws, size_t ws_size,
                              hipStream_t stream) {
    const float* x = (const float*)d_in[0];
    const float* W1 = (const float*)d_in[1];
    const float* b1 = (const float*)d_in[2];
    const float* W2 = (const float*)d_in[3];
    const float* b2 = (const float*)d_in[4];
    const float* Wp = (const float*)d_in[5];
    float* out = (float*)d_out;

    char* wsb = (char*)d_ws;
    size_t off = 0;
    auto carve = [&](size_t bytes) {
        void* p = wsb + off;
        off += (bytes + 255) & ~(size_t)255;
        return p;
    };
    const size_t w1f_e = (size_t)28 * 30 * 48 * 512;
    const size_t w2f_e = (size_t)28 * 72 * 12 * 512;
    const size_t wpb_e = (size_t)NOUT * NT;
    const size_t buf_e = (size_t)NB * NT * ND;
    const size_t dc_e = (size_t)NB * 512 * ND;
    const size_t h_e = (size_t)1040 * NB * NCH;
    const size_t i2_e = (size_t)NB * ND * NT;

    u16* W1f = (u16*)carve(sizeof(u16) * w1f_e);
    u16* W2f = (u16*)carve(sizeof(u16) * w2f_e);
    u16* Wpb = (u16*)carve(sizeof(u16) * wpb_e);
    u16* bufb = (u16*)carve(sizeof(u16) * buf_e);
    u16* dbufb = (u16*)carve(sizeof(u16) * dc_e);
    u16* cbufb = (u16*)carve(sizeof(u16) * dc_e);
    u16* h = (u16*)carve(sizeof(u16) * h_e);
    u16* in2T = (u16*)carve(sizeof(u16) * i2_e);
    if (off > ws_size) return;

    cvt8<<<(int)(buf_e / 8 / 256), 256, 0, stream>>>(x, bufb, (int)(buf_e / 8));
    cvt8<<<(int)(wpb_e / 8 / 256), 256, 0, stream>>>(Wp, Wpb, (int)(wpb_e / 8));
    w1fk<<<28 * 24, 256, 0, stream>>>(W1, W1f);
    w2fk<<<28 * 12 * 2, 256, 0, stream>>>(W2, W2f);

    for (int lvl = 0; lvl < 3; ++lvl) {
        int L = 512 >> lvl, nodes = 1 << lvl, Lout = L + 2;
        int mT1 = (NB * Lout + 63) / 64;
        dim3 g1(6 * mT1, 1, 2 * nodes);
        dim3 g2(NB * L / 64, 2, 2 * nodes);
        conv1m<<<g1, 256, 0, stream>>>(bufb, dbufb, cbufb, W1f, b1, h, lvl, 0);
        conv2m<<<g2, 256, 0, stream>>>(bufb, dbufb, cbufb, W2f, b2, h, lvl, 0);
        conv1m<<<g1, 256, 0, stream>>>(bufb, dbufb, cbufb, W1f, b1, h, lvl, 1);
        conv2m<<<g2, 256, 0, stream>>>(bufb, dbufb, cbufb, W2f, b2, h, lvl, 1);
    }
    mkin2T<<<dim3(3, 16, NB), 256, 0, stream>>>(bufb, x, in2T);
    projm<<<dim3(16, NB), 256, 0, stream>>>(in2T, Wpb, out);
}